// Round 1
// baseline (522.963 us; speedup 1.0000x reference)
//
#include <hip/hip_runtime.h>

// LocalAttention: B=4, N=4096, DIM=1024, H=16, HD=64, WINDOW=256, EXT=128
// Pipeline: convert->bf16, QKV GEMM (MFMA), V transpose, windowed attention (MFMA),
// proj GEMM (MFMA). Workspace need: ~176 MB.

typedef __attribute__((ext_vector_type(8))) short short8;
typedef __attribute__((ext_vector_type(4))) float f32x4;
typedef __attribute__((ext_vector_type(8))) unsigned short ushort8v;
typedef __attribute__((ext_vector_type(4))) unsigned short ushort4v;
typedef __attribute__((ext_vector_type(4))) unsigned int uint4v;

#define K_DIM 1024
#define M_TOT 16384

__device__ __forceinline__ unsigned short f2bf(float f) {
  unsigned int u = __builtin_bit_cast(unsigned int, f);
  u += 0x7FFFu + ((u >> 16) & 1u);
  return (unsigned short)(u >> 16);
}
__device__ __forceinline__ unsigned short f2h(float f) {
  _Float16 h = (_Float16)f;
  return __builtin_bit_cast(unsigned short, h);
}
__device__ __forceinline__ float h2f(unsigned short u) {
  _Float16 h = __builtin_bit_cast(_Float16, u);
  return (float)h;
}

// ---------------- fp32 -> bf16 convert ----------------
__global__ __launch_bounds__(256) void convf2b(const float* __restrict__ src,
                                               unsigned short* __restrict__ dst, int n4) {
  int i = blockIdx.x * blockDim.x + threadIdx.x;
  if (i >= n4) return;
  f32x4 v = *(const f32x4*)(src + (size_t)i * 4);
  ushort4v o;
  o[0] = f2bf(v[0]); o[1] = f2bf(v[1]); o[2] = f2bf(v[2]); o[3] = f2bf(v[3]);
  *(ushort4v*)(dst + (size_t)i * 4) = o;
}

// ---------------- shared GEMM core: C(128x128) = A * Bw^T ----------------
// A: [M x 1024] bf16 row-major, Bw: [F x 1024] bf16 row-major (both K-contiguous).
__device__ __forceinline__ void gemm_core(const unsigned short* __restrict__ A,
                                          const unsigned short* __restrict__ Bw,
                                          unsigned short* As, unsigned short* Bs,
                                          int m0, int f0, int tid, f32x4 acc[4][4]) {
  const int lane = tid & 63;
  const int wm = (tid >> 7) & 1;
  const int wn = (tid >> 6) & 1;
  for (int kk = 0; kk < K_DIM; kk += 32) {
    // stage 128x32 A-tile and B-tile (8KB each): 512 chunks of 16B, 2 per thread each
#pragma unroll
    for (int r = 0; r < 2; ++r) {
      int c = tid + r * 256;
      int row = c >> 2, seg = c & 3;
      uint4v va = *(const uint4v*)(A + (size_t)(m0 + row) * K_DIM + kk + seg * 8);
      uint4v vb = *(const uint4v*)(Bw + (size_t)(f0 + row) * K_DIM + kk + seg * 8);
      *(uint4v*)&As[c * 8] = va;
      *(uint4v*)&Bs[c * 8] = vb;
    }
    __syncthreads();
    short8 af[4], bf[4];
#pragma unroll
    for (int i = 0; i < 4; ++i)
      af[i] = *(const short8*)&As[(wm * 64 + i * 16 + (lane & 15)) * 32 + (lane >> 4) * 8];
#pragma unroll
    for (int j = 0; j < 4; ++j)
      bf[j] = *(const short8*)&Bs[(wn * 64 + j * 16 + (lane & 15)) * 32 + (lane >> 4) * 8];
#pragma unroll
    for (int i = 0; i < 4; ++i)
#pragma unroll
      for (int j = 0; j < 4; ++j)
        acc[i][j] = __builtin_amdgcn_mfma_f32_16x16x32_bf16(af[i], bf[j], acc[i][j], 0, 0, 0);
    __syncthreads();
  }
}

// ---------------- QKV GEMM + bias + scatter to per-head q/k/v ----------------
__global__ __launch_bounds__(256) void gemm_qkv(const unsigned short* __restrict__ A,
                                                const unsigned short* __restrict__ Bw,
                                                const float* __restrict__ bias,
                                                unsigned short* __restrict__ q,
                                                unsigned short* __restrict__ k,
                                                unsigned short* __restrict__ v) {
  __shared__ unsigned short As[128 * 32];
  __shared__ unsigned short Bs[128 * 32];
  int m0 = (blockIdx.x & 127) * 128;           // M_TOT/128 = 128 tiles
  int f0 = (blockIdx.x >> 7) * 128;            // 24 f-tiles
  int tid = threadIdx.x;
  f32x4 acc[4][4] = {};
  gemm_core(A, Bw, As, Bs, m0, f0, tid, acc);
  int lane = tid & 63;
  int wm = (tid >> 7) & 1, wn = (tid >> 6) & 1;
#pragma unroll
  for (int j = 0; j < 4; ++j) {
    int f = f0 + wn * 64 + j * 16 + (lane & 15);
    int which = f >> 10;
    int hh = (f >> 6) & 15;
    int d = f & 63;
    unsigned short* dst = (which == 0) ? q : ((which == 1) ? k : v);
    float bj = bias[f];
#pragma unroll
    for (int i = 0; i < 4; ++i) {
#pragma unroll
      for (int r = 0; r < 4; ++r) {
        int m = m0 + wm * 64 + i * 16 + (lane >> 4) * 4 + r;
        int bb = m >> 12, n = m & 4095;
        dst[((size_t)(bb * 16 + hh) * 4096 + n) * 64 + d] = f2bf(acc[i][j][r] + bj);
      }
    }
  }
}

// ---------------- proj GEMM + bias -> fp32 out ----------------
__global__ __launch_bounds__(256) void gemm_proj(const unsigned short* __restrict__ A,
                                                 const unsigned short* __restrict__ Bw,
                                                 const float* __restrict__ bias,
                                                 float* __restrict__ out) {
  __shared__ unsigned short As[128 * 32];
  __shared__ unsigned short Bs[128 * 32];
  int m0 = (blockIdx.x & 127) * 128;
  int f0 = (blockIdx.x >> 7) * 128;            // 8 f-tiles
  int tid = threadIdx.x;
  f32x4 acc[4][4] = {};
  gemm_core(A, Bw, As, Bs, m0, f0, tid, acc);
  int lane = tid & 63;
  int wm = (tid >> 7) & 1, wn = (tid >> 6) & 1;
#pragma unroll
  for (int j = 0; j < 4; ++j) {
    int f = f0 + wn * 64 + j * 16 + (lane & 15);
    float bj = bias[f];
#pragma unroll
    for (int i = 0; i < 4; ++i) {
#pragma unroll
      for (int r = 0; r < 4; ++r) {
        int m = m0 + wm * 64 + i * 16 + (lane >> 4) * 4 + r;
        out[(size_t)m * 1024 + f] = acc[i][j][r] + bj;
      }
    }
  }
}

// ---------------- V transpose: (B,H,4096,64) -> (B,H,64,4096) ----------------
__global__ __launch_bounds__(256) void transpose_v(const unsigned short* __restrict__ v,
                                                   unsigned short* __restrict__ vt) {
  __shared__ unsigned short tile[64][72];      // pad to break bank conflicts
  int bid = blockIdx.x;                        // 64 bh * 64 n-tiles
  int bh = bid >> 6;
  int n0 = (bid & 63) * 64;
  int tid = threadIdx.x;
#pragma unroll
  for (int r = 0; r < 2; ++r) {
    int c = tid + r * 256;                     // 0..511
    int row = c >> 3, col8 = (c & 7) * 8;
    uint4v dv = *(const uint4v*)&v[((size_t)bh * 4096 + n0 + row) * 64 + col8];
    *(uint4v*)&tile[row][col8] = dv;           // (72*row+col8)*2 is 16B aligned
  }
  __syncthreads();
#pragma unroll
  for (int r = 0; r < 2; ++r) {
    int c = tid + r * 256;
    int d = c >> 3, n8 = (c & 7) * 8;
    ushort8v o;
#pragma unroll
    for (int ii = 0; ii < 8; ++ii) o[ii] = tile[n8 + ii][d];
    *(ushort8v*)&vt[((size_t)bh * 64 + d) * 4096 + n0 + n8] = o;
  }
}

// ---------------- windowed attention ----------------
// Block: 32 queries of one (b,h,group). Keys: 512-wide window [g*256-128, g*256+384).
// Phase1: S = Q K^T * scale (fp16 in LDS, wave w handles 128 keys)
// Phase2: row max/sum + P=exp(S-m) (bf16 back into LDS)
// Phase3: O = P V via MFMA (Vt gives contiguous B-fragments), normalize, store bf16.
#define SLD 520

__global__ __launch_bounds__(256) void attn_kernel(const unsigned short* __restrict__ Q,
                                                   const unsigned short* __restrict__ Kb,
                                                   const unsigned short* __restrict__ Vt,
                                                   unsigned short* __restrict__ Ao) {
  __shared__ unsigned short S[32 * SLD];
  __shared__ float smax[4][32];
  __shared__ float psum[32][8];
  __shared__ float invl[32];

  int bid = blockIdx.x;
  int qq = bid & 7;
  int g = (bid >> 3) & 15;
  int h = (bid >> 7) & 15;
  int b = bid >> 11;
  int bh = b * 16 + h;
  int q0 = g * 256 + qq * 32;
  int kst = g * 256 - 128;
  int tid = threadIdx.x, lane = tid & 63, w = tid >> 6;
  const size_t base = (size_t)bh * 4096 * 64;

  // ---- Phase 1 ----
  short8 aq[2][2];
#pragma unroll
  for (int mt = 0; mt < 2; ++mt)
#pragma unroll
    for (int s = 0; s < 2; ++s)
      aq[mt][s] = *(const short8*)&Q[base + (size_t)(q0 + mt * 16 + (lane & 15)) * 64 +
                                     s * 32 + (lane >> 4) * 8];

  float rmax[2][4];
#pragma unroll
  for (int mt = 0; mt < 2; ++mt)
#pragma unroll
    for (int r = 0; r < 4; ++r) rmax[mt][r] = -1e30f;

  for (int t = 0; t < 8; ++t) {
    int kk0 = w * 128 + t * 16;
    int nk = kst + kk0 + (lane & 15);
    int nkc = min(max(nk, 0), 4095);
    short8 bk[2];
#pragma unroll
    for (int s = 0; s < 2; ++s)
      bk[s] = *(const short8*)&Kb[base + (size_t)nkc * 64 + s * 32 + (lane >> 4) * 8];
    f32x4 accs[2] = {};
#pragma unroll
    for (int mt = 0; mt < 2; ++mt)
#pragma unroll
      for (int s = 0; s < 2; ++s)
        accs[mt] = __builtin_amdgcn_mfma_f32_16x16x32_bf16(aq[mt][s], bk[s], accs[mt], 0, 0, 0);
    bool valid = (nk >= 0) && (nk < 4096);
#pragma unroll
    for (int mt = 0; mt < 2; ++mt)
#pragma unroll
      for (int r = 0; r < 4; ++r) {
        float sv = valid ? accs[mt][r] * 0.125f : -__builtin_inff();
        int row = mt * 16 + (lane >> 4) * 4 + r;
        S[row * SLD + kk0 + (lane & 15)] = f2h(sv);
        rmax[mt][r] = fmaxf(rmax[mt][r], sv);
      }
  }
#pragma unroll
  for (int mt = 0; mt < 2; ++mt)
#pragma unroll
    for (int r = 0; r < 4; ++r) {
      float m_ = rmax[mt][r];
#pragma unroll
      for (int off = 1; off < 16; off <<= 1) m_ = fmaxf(m_, __shfl_xor(m_, off, 64));
      rmax[mt][r] = m_;
    }
  if ((lane & 15) == 0) {
#pragma unroll
    for (int mt = 0; mt < 2; ++mt)
#pragma unroll
      for (int r = 0; r < 4; ++r)
        smax[w][mt * 16 + (lane >> 4) * 4 + r] = rmax[mt][r];
  }
  __syncthreads();

  // ---- Phase 2 ----
  {
    int row = tid >> 3, seg = tid & 7;
    float mr = fmaxf(fmaxf(smax[0][row], smax[1][row]), fmaxf(smax[2][row], smax[3][row]));
    float sum = 0.f;
    unsigned short* Sr = &S[row * SLD + seg * 64];
#pragma unroll
    for (int c = 0; c < 64; c += 4) {
      ushort4v u = *(ushort4v*)&Sr[c];
#pragma unroll
      for (int ii = 0; ii < 4; ++ii) {
        float p = __expf(h2f(u[ii]) - mr);
        sum += p;
        u[ii] = f2bf(p);
      }
      *(ushort4v*)&Sr[c] = u;
    }
    psum[row][seg] = sum;
  }
  __syncthreads();
  if (tid < 32) {
    float s = 0.f;
#pragma unroll
    for (int kk = 0; kk < 8; ++kk) s += psum[tid][kk];
    invl[tid] = 1.0f / s;
  }
  __syncthreads();

  // ---- Phase 3 ----
  {
    int mt = w >> 1, dh = w & 1;
    f32x4 acco[2] = {};
    for (int ks = 0; ks < 16; ++ks) {
      short8 ap = *(const short8*)&S[(mt * 16 + (lane & 15)) * SLD + ks * 32 + (lane >> 4) * 8];
      int nk = kst + ks * 32 + (lane >> 4) * 8;
      int nkc = min(max(nk, 0), 4096 - 8);  // fragments never straddle validity boundary
#pragma unroll
      for (int nt = 0; nt < 2; ++nt) {
        int d = dh * 32 + nt * 16 + (lane & 15);
        short8 bv = *(const short8*)&Vt[((size_t)bh * 64 + d) * 4096 + nkc];
        acco[nt] = __builtin_amdgcn_mfma_f32_16x16x32_bf16(ap, bv, acco[nt], 0, 0, 0);
      }
    }
#pragma unroll
    for (int nt = 0; nt < 2; ++nt) {
      int d = dh * 32 + nt * 16 + (lane & 15);
#pragma unroll
      for (int r = 0; r < 4; ++r) {
        int lrow = mt * 16 + (lane >> 4) * 4 + r;
        float o = acco[nt][r] * invl[lrow];
        Ao[(size_t)(b * 4096 + q0 + lrow) * 1024 + h * 64 + d] = f2bf(o);
      }
    }
  }
}

// ---------------- host ----------------
extern "C" void kernel_launch(void* const* d_in, const int* in_sizes, int n_in,
                              void* d_out, int out_size, void* d_ws, size_t ws_size,
                              hipStream_t stream) {
  const float* x = (const float*)d_in[0];
  const float* w_qkv = (const float*)d_in[1];
  const float* b_qkv = (const float*)d_in[2];
  const float* w_proj = (const float*)d_in[3];
  const float* b_proj = (const float*)d_in[4];
  float* out = (float*)d_out;

  unsigned short* ws = (unsigned short*)d_ws;
  unsigned short* xb = ws;                       // 16777216 elems (reused as vt later)
  unsigned short* wqkvb = ws + 16777216;         // 3145728
  unsigned short* wprojb = ws + 19922944;        // 1048576
  unsigned short* qb = ws + 20971520;            // 16777216
  unsigned short* kb = ws + 37748736;            // 16777216
  unsigned short* vb = ws + 54525952;            // 16777216
  unsigned short* attnb = ws + 71303168;         // 16777216  (total ~176 MB)
  unsigned short* vtb = xb;                      // alias: xb dead after gemm_qkv

  convf2b<<<16384, 256, 0, stream>>>(x, xb, 16777216 / 4);
  convf2b<<<3072, 256, 0, stream>>>(w_qkv, wqkvb, 3145728 / 4);
  convf2b<<<1024, 256, 0, stream>>>(w_proj, wprojb, 1048576 / 4);
  gemm_qkv<<<128 * 24, 256, 0, stream>>>(xb, wqkvb, b_qkv, qb, kb, vb);
  transpose_v<<<4096, 256, 0, stream>>>(vb, vtb);
  attn_kernel<<<8192, 256, 0, stream>>>(qb, kb, vtb, attnb);
  gemm_proj<<<128 * 8, 256, 0, stream>>>(attnb, wprojb, b_proj, out);
}